// Round 7
// baseline (1011.395 us; speedup 1.0000x reference)
//
#include <hip/hip_runtime.h>
#include <stdint.h>

typedef float v4f __attribute__((ext_vector_type(4)));
typedef short bf16x8 __attribute__((ext_vector_type(8)));
typedef int v4i __attribute__((ext_vector_type(4)));
typedef int v8i __attribute__((ext_vector_type(8)));
typedef unsigned int uint32;
typedef unsigned long long u64;

#define V_N 30000
#define E_N 300
#define EPAD 320
#define H_N 256
#define G_N 1024
#define B_N 64
#define S_N 512
#define T_N 9

// workspace layout (bytes)
#define OFF_EMB  ((size_t)0)            // [V][320] bf16          19,200,000
#define OFF_WIH  ((size_t)19200000)     // [2][1024][320] bf16     1,310,720
#define OFF_WHH  ((size_t)20510720)     // [2][16][4][2][64][32B]    524,288
#define OFF_PRE  ((size_t)21035008)     // [2][512][4][64][64] 8B 134,217,728
#define OFF_H    ((size_t)155252736)    // [64][512][512] f32      67,108,864

__device__ __forceinline__ uint32 bf16r(float x){
  uint32 u = __float_as_uint(x);
  u += 0x7FFFu + ((u>>16)&1u);
  return u>>16;
}
__device__ __forceinline__ float sigm(float x){
  return __builtin_amdgcn_rcpf(1.f + __builtin_amdgcn_exp2f(-1.4426950408889634f*x));
}
__device__ __forceinline__ float tanh_(float x){
  return 1.f - 2.f*__builtin_amdgcn_rcpf(1.f + __builtin_amdgcn_exp2f(2.8853900817779268f*x));
}

// ---------------- conversions: emb + Wih -> bf16 padded to K=320; also zero out[0] ----------------
__global__ void k_convert(const float* __restrict__ emb,
                          const float* __restrict__ wih_f,
                          const float* __restrict__ wih_b,
                          char* __restrict__ ws, float* __restrict__ out){
  int tid = blockIdx.x*256 + threadIdx.x;
  if (tid == 0) out[0] = 0.f;
  const int NE = V_N*40;
  unsigned short* eo = (unsigned short*)(ws + OFF_EMB);
  unsigned short* wo = (unsigned short*)(ws + OFF_WIH);
  const float* src; unsigned short* dst; int g;
  if (tid < NE){
    int row = tid/40; g = tid%40;
    src = emb + (size_t)row*E_N;
    dst = eo + (size_t)row*EPAD + g*8;
  } else if (tid < NE + 2*G_N*40){
    int t2 = tid - NE;
    int dir = t2/(G_N*40); int r2 = t2%(G_N*40);
    int row = r2/40; g = r2%40;
    src = (dir? wih_b : wih_f) + (size_t)row*E_N;
    dst = wo + ((size_t)dir*G_N + row)*EPAD + g*8;
  } else return;
  unsigned short v[8];
  #pragma unroll
  for (int j=0;j<8;j++){
    int c = g*8+j;
    float x = (c < E_N)? src[c] : 0.f;
    v[j] = (unsigned short)bf16r(x);
  }
  uint4 pk;
  pk.x = (uint32)v[0] | ((uint32)v[1]<<16);
  pk.y = (uint32)v[2] | ((uint32)v[3]<<16);
  pk.z = (uint32)v[4] | ((uint32)v[5]<<16);
  pk.w = (uint32)v[6] | ((uint32)v[7]<<16);
  *(uint4*)dst = pk;
}

// ---------------- Whh -> fp8 e4m3 (x64), 16x16x128 B-layout ----------------
// u64 idx = tid: [dir(1)|w(4)|g(2)|kk(1)|lane(6)|part(2)]
// B frag for tile ct=g*16+w: col = lane&15 (unit w*16+n), k = kk*128+(lane>>4)*32+part*8+j
__global__ void k_whh(const float* __restrict__ whh_f, const float* __restrict__ whh_b,
                      char* __restrict__ ws){
  int tid = blockIdx.x*256 + threadIdx.x;   // 65536 total
  int part = tid&3;
  int lane = (tid>>2)&63;
  int kk = (tid>>8)&1, g = (tid>>9)&3, w = (tid>>11)&15, dir = (tid>>15)&1;
  const float* W = dir? whh_b : whh_f;
  int n = lane&15, lq = lane>>4;
  int col = g*256 + w*16 + n;                 // gate*256 + unit
  int k0  = kk*128 + lq*32 + part*8;
  const float* p = W + (size_t)col*H_N + k0;
  int lo = __builtin_amdgcn_cvt_pk_fp8_f32(p[0]*64.f, p[1]*64.f, 0, false);
  lo = __builtin_amdgcn_cvt_pk_fp8_f32(p[2]*64.f, p[3]*64.f, lo, true);
  int hi = __builtin_amdgcn_cvt_pk_fp8_f32(p[4]*64.f, p[5]*64.f, 0, false);
  hi = __builtin_amdgcn_cvt_pk_fp8_f32(p[6]*64.f, p[7]*64.f, hi, true);
  u64 vv = (uint32)lo | ((u64)(uint32)hi<<32);
  ((u64*)(ws+OFF_WHH))[tid] = vv;
}

// ---------------- input projection: pre = emb[ids] @ Wih^T + bias (bf16 MFMA) -------------
__global__ __launch_bounds__(256,2)
void k_gemm1(const int* __restrict__ ids, char* __restrict__ ws,
             const float* __restrict__ bih_f, const float* __restrict__ bhh_f,
             const float* __restrict__ bih_b, const float* __restrict__ bhh_b){
  int bx = blockIdx.x;                      // [dir(2)][tp(256)][nc(8)]
  int nc = bx & 7, tp = (bx>>3)&255, dir = bx>>11;
  const unsigned short* embb = (const unsigned short*)(ws+OFF_EMB);
  const unsigned short* wihb = (const unsigned short*)(ws+OFF_WIH) + (size_t)dir*G_N*EPAD;
  __shared__ unsigned short Asl[128*32];
  __shared__ unsigned short Bsl[128*32];
  __shared__ int ids_s[128];
  int tid = threadIdx.x, lane = tid&63, w = tid>>6;
  if (tid < 128){
    int t = tp*2 + (tid>>6), b = tid&63;
    ids_s[tid] = ids[b*S_N + t];
  }
  __syncthreads();
  v4f acc[2][8];
  #pragma unroll
  for (int i=0;i<2;i++)
    #pragma unroll
    for (int j=0;j<8;j++) acc[i][j] = (v4f){0.f,0.f,0.f,0.f};
  int r = tid>>1, hf = tid&1;
  int n0 = lane&15, q = lane>>4;
  const float* bi = dir? bih_b : bih_f;
  const float* bh = dir? bhh_b : bhh_f;
  float bv[8];
  #pragma unroll
  for (int nt=0; nt<8; nt++){
    int c = nc*128 + nt*16 + n0;
    bv[nt] = bi[c] + bh[c];
  }
  for (int ks=0; ks<10; ks++){
    const float4* pa = (const float4*)(embb + (size_t)ids_s[r]*EPAD + ks*32 + hf*16);
    float4 a0 = pa[0], a1 = pa[1];
    const float4* pb = (const float4*)(wihb + (size_t)(nc*128 + r)*EPAD + ks*32 + hf*16);
    float4 b0 = pb[0], b1 = pb[1];
    __syncthreads();
    float4* da = (float4*)(Asl + r*32 + hf*16); da[0]=a0; da[1]=a1;
    float4* db = (float4*)(Bsl + r*32 + hf*16); db[0]=b0; db[1]=b1;
    __syncthreads();
    bf16x8 bfr[8], afr[2];
    #pragma unroll
    for (int nt=0; nt<8; nt++) bfr[nt] = *(const bf16x8*)(Bsl + (nt*16+n0)*32 + q*8);
    afr[0] = *(const bf16x8*)(Asl + (w*16+n0)*32 + q*8);
    afr[1] = *(const bf16x8*)(Asl + ((w+4)*16+n0)*32 + q*8);
    #pragma unroll
    for (int mi=0; mi<2; mi++)
      #pragma unroll
      for (int nt=0; nt<8; nt++)
        acc[mi][nt] = __builtin_amdgcn_mfma_f32_16x16x32_bf16(afr[mi], bfr[nt], acc[mi][nt], 0,0,0);
  }
  uint2* pre = (uint2*)(ws + OFF_PRE);
  #pragma unroll
  for (int mi=0; mi<2; mi++){
    int t = tp*2 + mi;
    #pragma unroll
    for (int nt=0; nt<8; nt++){
      int ct = nc*8 + nt;
      size_t tile = (((size_t)(dir*S_N + t)*4 + w)*64 + ct);
      v4f a = acc[mi][nt];
      uint2 o;
      o.x = bf16r(a[0]+bv[nt]) | (bf16r(a[1]+bv[nt])<<16);
      o.y = bf16r(a[2]+bv[nt]) | (bf16r(a[3]+bv[nt])<<16);
      pre[tile*64 + lane] = o;
    }
  }
}

// ---------------- recurrence: 16 waves/WG (4/SIMD), act-direct epilogue ----------------
// grid 64: [dir(1)][bg(2)][q(3)], block 1024. Wave w (0..15) owns units [16w,16w+16)
// (tiles ct = g*16+w, g=0..3). WG q owns batch slots {q,q+8}; act lanes: quads
// {q>>2,(q>>2)+2}; C-reg R0=q&3. h f32 staged in LDS, flushed full-line by waves 0..7.
#define MFMA_SC(A,B,C) __builtin_amdgcn_mfma_scale_f32_16x16x128_f8f6f4( \
    (A), (B), (C), 0, 0, 0, 0x7F7F7F7F, 0, 0x75757575)

#define STEP(HBR, HBW, WB, SB, FIRSTF) do { \
  while (vc[0] < need) __builtin_amdgcn_s_sleep(1); \
  v8i afr0, afr1; \
  { v4i lo = *(const v4i*)((HBR) + ab); v4i hi = *(const v4i*)((HBR) + ab + 16); \
    afr0 = __builtin_shufflevector(lo,hi,0,1,2,3,4,5,6,7); } \
  _Pragma("unroll") \
  for (int g=0; g<4; g++) acc[g][R0] = __uint_as_float(pr[g]<<16); \
  if (act){ \
    _Pragma("unroll") \
    for (int g=0; g<4; g++) pr[g] = *(const unsigned short*)(pp + voff[g]); } \
  pp += sstride; \
  _Pragma("unroll") \
  for (int g=0; g<4; g++) acc[g] = MFMA_SC(afr0, Wf[g][0], acc[g]); \
  while (vc[1] < need) __builtin_amdgcn_s_sleep(1); \
  { v4i lo = *(const v4i*)((HBR) + ab + 128); v4i hi = *(const v4i*)((HBR) + ab + 144); \
    afr1 = __builtin_shufflevector(lo,hi,0,1,2,3,4,5,6,7); } \
  _Pragma("unroll") \
  for (int g=0; g<4; g++) acc[g] = MFMA_SC(afr1, Wf[g][1], acc[g]); \
  need += 8; \
  if (act){ \
    float si = sigm(acc[0][R0]), sf = sigm(acc[1][R0]); \
    float tg = tanh_(acc[2][R0]), so = sigm(acc[3][R0]); \
    c0 = sf*c0 + si*tg; \
    float h = so * tanh_(c0); \
    int pk8 = __builtin_amdgcn_cvt_pk_fp8_f32(h*16.f, 0.f, 0, false); \
    (HBW)[hb_off] = (char)(pk8 & 0xFF); \
    hst[(WB)*512 + hs_off] = h; \
  } \
  if (do_store && !(FIRSTF)){ \
    float hv = hst[(SB)*512 + chunk]; \
    *sp = hv; sp += hstride; \
  } \
  if (lane == 0) atomicAdd(&ctrs[hw], 1); \
} while(0)

template<int R0>
__device__ __forceinline__ void lstm_loop(
    const char* pp, int sstride, const int* voff,
    int ab, const v8i (*Wf)[2], bool act,
    char* hb0, char* hb1, int hb_off,
    float* hst, int hs_off, int chunk, bool do_store,
    float* sp, int hstride, int lane, int hw,
    volatile int* vc, int* ctrs)
{
  uint32 pr[4] = {0u,0u,0u,0u};
  if (act){
    #pragma unroll
    for (int g=0; g<4; g++) pr[g] = *(const unsigned short*)(pp + voff[g]);
  }
  pp += sstride;
  v4f acc[4];
  #pragma unroll
  for (int g=0; g<4; g++) acc[g] = (v4f){0.f,0.f,0.f,0.f};
  float c0 = 0.f;
  int need = 0;
  #pragma unroll 1
  for (int pair=0; pair<256; pair++){
    bool first = (pair == 0);
    STEP(hb0, hb1, 0, 1, first);   // even step s: read hb0, write hb1, hst buf 0, store buf 1
    STEP(hb1, hb0, 1, 0, false);   // odd  step s: read hb1, write hb0, hst buf 1, store buf 0
  }
  // final flush: h(511) lives in hst buf 1
  while (vc[0] < need) __builtin_amdgcn_s_sleep(1);
  while (vc[1] < need) __builtin_amdgcn_s_sleep(1);
  if (do_store) *sp = hst[512 + chunk];
}

__global__ __launch_bounds__(1024,1)
void k_lstm(char* __restrict__ ws){
  int bx = blockIdx.x;
  int q = bx&7, bg = (bx>>3)&3, dir = bx>>5;
  int tid = threadIdx.x, lane = tid&63, w = tid>>6;   // w = 0..15
  int n0 = lane&15, lq = lane>>4;
  __shared__ char hbuf[2][16*272];       // h (fp8 x16), stride 272
  __shared__ float hst[2*512];           // h f32 staging (2 slots x 256), dbuf
  __shared__ int ctrs[2];
  for (int i=tid; i<2176; i+=1024) ((int*)hbuf)[i] = 0;
  if (tid < 2) ctrs[tid] = 0;
  // weights: per (dir,w) 16 KB block = 512 v8i; per (g,kk): 64 lanes x 32 B
  const v8i* wp = (const v8i*)(ws + OFF_WHH) + (size_t)(dir*16 + w)*512;
  v8i Wf[4][2];
  #pragma unroll
  for (int g=0; g<4; g++)
    #pragma unroll
    for (int kk=0; kk<2; kk++)
      Wf[g][kk] = wp[(g*2+kk)*64 + lane];
  // ---- precomputed step-invariant state ----
  int st0 = dir? (S_N-1) : 0;
  const char* pp = ws + OFF_PRE + (size_t)dir*67108864 + (size_t)(st0*4 + bg)*32768;
  const int sstride = dir? -131072 : 131072;
  int R0r = q&3;
  int voff[4];
  #pragma unroll
  for (int g=0; g<4; g++){
    int ct = g*16 + w;
    voff[g] = (ct*64 + lane)*8 + R0r*2;
  }
  int ab = n0*272 + lq*32;               // afr base: row n0, k = lq*32 (+128 for kk1)
  int a = q>>2;
  bool act = ((lq & 1) == a);
  int half = (lq>>1)&1;                  // quad a -> 0, quad a+2 -> 1
  int slot = q + half*8;
  int u0 = w*16 + n0;
  int hb_off = slot*272 + u0;
  int hs_off = half*256 + u0;
  int chunk = (w&7)*64 + lane;           // flush assignment for waves 0..7
  bool do_store = (w < 8);
  float* hout = (float*)(ws+OFF_H);
  int sb = bg*16 + q + (chunk>>8)*8;
  int su = chunk & 255;
  float* sp = hout + ((size_t)sb*S_N + st0)*512 + dir*256 + su;
  const int hstride = dir? -512 : 512;
  int hw = (w >= 8);
  volatile int* vc = (volatile int*)ctrs;
  __syncthreads();
  switch (R0r){
    case 0: lstm_loop<0>(pp, sstride, voff, ab, Wf, act, hbuf[0], hbuf[1], hb_off, hst, hs_off, chunk, do_store, sp, hstride, lane, hw, vc, ctrs); break;
    case 1: lstm_loop<1>(pp, sstride, voff, ab, Wf, act, hbuf[0], hbuf[1], hb_off, hst, hs_off, chunk, do_store, sp, hstride, lane, hw, vc, ctrs); break;
    case 2: lstm_loop<2>(pp, sstride, voff, ab, Wf, act, hbuf[0], hbuf[1], hb_off, hst, hs_off, chunk, do_store, sp, hstride, lane, hw, vc, ctrs); break;
    default: lstm_loop<3>(pp, sstride, voff, ab, Wf, act, hbuf[0], hbuf[1], hb_off, hst, hs_off, chunk, do_store, sp, hstride, lane, hw, vc, ctrs); break;
  }
}

// ---------------- classifier: one wave per token, f32 ----------------
__global__ __launch_bounds__(256)
void k_clf(const char* __restrict__ ws, const float* __restrict__ clfW,
           const float* __restrict__ clfb, float* __restrict__ out){
  int wid = (blockIdx.x*256 + threadIdx.x)>>6;
  int lane = threadIdx.x & 63;
  const float4* h = (const float4*)((const float*)(ws+OFF_H) + (size_t)wid*512);
  float4 h0 = h[lane*2], h1 = h[lane*2+1];
  float a[9];
  #pragma unroll
  for (int t=0;t<9;t++){
    const float4* wp = (const float4*)(clfW + t*512);
    float4 w0 = wp[lane*2], w1 = wp[lane*2+1];
    a[t] = h0.x*w0.x + h0.y*w0.y + h0.z*w0.z + h0.w*w0.w
         + h1.x*w1.x + h1.y*w1.y + h1.z*w1.z + h1.w*w1.w;
  }
  #pragma unroll
  for (int t=0;t<9;t++){
    #pragma unroll
    for (int m=32;m>=1;m>>=1) a[t] += __shfl_xor(a[t], m, 64);
  }
  float val = a[0];
  #pragma unroll
  for (int t=1;t<9;t++) val = (lane==t)? a[t] : val;
  if (lane<9) out[1 + (size_t)wid*9 + lane] = val + clfb[lane];
}

// ---------------- CRF ----------------
__global__ __launch_bounds__(64)
void k_crf(const int* __restrict__ labels, const float* __restrict__ start_t,
           const float* __restrict__ end_t, const float* __restrict__ trans,
           float* __restrict__ out){
  int b = blockIdx.x, lane = threadIdx.x;
  const float* em = out + 1 + (size_t)b*S_N*T_N;
  const int* tg = labels + (size_t)b*S_N;
  float scv = 0.f;
  for (int t=lane; t<S_N; t+=64){
    int ct = tg[t];
    float e = em[t*T_N + ct];
    if (t==0) scv += start_t[ct] + e;
    else scv += trans[tg[t-1]*T_N + ct] + e;
  }
  if (lane==0) scv += end_t[tg[S_N-1]];
  #pragma unroll
  for (int m=32;m>=1;m>>=1) scv += __shfl_xor(scv, m, 64);
  int j = (lane<9)? lane : 0;
  float wt[9];
  #pragma unroll
  for (int i=0;i<9;i++) wt[i] = trans[i*T_N + j];
  float alpha = start_t[j] + em[j];
  #pragma unroll 1
  for (int t=1;t<S_N;t++){
    float v[9]; float mx = -3.4e38f;
    #pragma unroll
    for (int i=0;i<9;i++){
      float av = __shfl(alpha, i, 64);
      v[i] = av + wt[i];
      mx = fmaxf(mx, v[i]);
    }
    float ss = 0.f;
    #pragma unroll
    for (int i=0;i<9;i++) ss += __builtin_amdgcn_exp2f(1.4426950408889634f*(v[i]-mx));
    alpha = mx + 0.6931471805599453f*__builtin_amdgcn_logf(ss) + em[t*T_N + j];
  }
  float av = (lane<9)? alpha + end_t[j] : -3.4e38f;
  float mx = av;
  #pragma unroll
  for (int m=32;m>=1;m>>=1) mx = fmaxf(mx, __shfl_xor(mx, m, 64));
  float es = (lane<9)? __builtin_amdgcn_exp2f(1.4426950408889634f*(av-mx)) : 0.f;
  #pragma unroll
  for (int m=32;m>=1;m>>=1) es += __shfl_xor(es, m, 64);
  float logZ = mx + 0.6931471805599453f*__builtin_amdgcn_logf(es);
  if (lane==0) atomicAdd(out, logZ - scv);
}

extern "C" void kernel_launch(void* const* d_in, const int* in_sizes, int n_in,
                              void* d_out, int out_size, void* d_ws, size_t ws_size,
                              hipStream_t stream){
  const int* ids      = (const int*)d_in[0];
  const int* labels   = (const int*)d_in[1];
  const float* emb    = (const float*)d_in[3];
  const float* wih_f  = (const float*)d_in[4];
  const float* whh_f  = (const float*)d_in[5];
  const float* bih_f  = (const float*)d_in[6];
  const float* bhh_f  = (const float*)d_in[7];
  const float* wih_b  = (const float*)d_in[8];
  const float* whh_b  = (const float*)d_in[9];
  const float* bih_b  = (const float*)d_in[10];
  const float* bhh_b  = (const float*)d_in[11];
  const float* clfW   = (const float*)d_in[12];
  const float* clfb   = (const float*)d_in[13];
  const float* start_t= (const float*)d_in[14];
  const float* end_t  = (const float*)d_in[15];
  const float* trans  = (const float*)d_in[16];
  float* out = (float*)d_out;
  char* ws = (char*)d_ws;

  hipLaunchKernelGGL(k_convert, dim3((V_N*40 + 2*G_N*40 + 255)/256), dim3(256), 0, stream,
                     emb, wih_f, wih_b, ws, out);
  hipLaunchKernelGGL(k_whh, dim3(256), dim3(256), 0, stream, whh_f, whh_b, ws);
  hipLaunchKernelGGL(k_gemm1, dim3(4096), dim3(256), 0, stream, ids, ws,
                     bih_f, bhh_f, bih_b, bhh_b);
  hipLaunchKernelGGL(k_lstm, dim3(64), dim3(1024), 0, stream, ws);
  hipLaunchKernelGGL(k_clf, dim3(8192), dim3(256), 0, stream, ws, clfW, clfb, out);
  hipLaunchKernelGGL(k_crf, dim3(64), dim3(64), 0, stream, labels, start_t, end_t, trans, out);
}

// Round 8
// 791.910 us; speedup vs baseline: 1.2772x; 1.2772x over previous
//
#include <hip/hip_runtime.h>
#include <stdint.h>

typedef float v4f __attribute__((ext_vector_type(4)));
typedef float v2f __attribute__((ext_vector_type(2)));
typedef short bf16x8 __attribute__((ext_vector_type(8)));
typedef int v4i __attribute__((ext_vector_type(4)));
typedef int v8i __attribute__((ext_vector_type(8)));
typedef unsigned int uint32;
typedef unsigned long long u64;

#define V_N 30000
#define E_N 300
#define EPAD 320
#define H_N 256
#define G_N 1024
#define B_N 64
#define S_N 512
#define T_N 9

// workspace layout (bytes)
#define OFF_EMB  ((size_t)0)            // [V][320] bf16          19,200,000
#define OFF_WIH  ((size_t)19200000)     // [2][1024][320] bf16     1,310,720
#define OFF_WHH  ((size_t)20510720)     // [2][8][8][2][64][32B]     524,288
#define OFF_PRE  ((size_t)21035008)     // [2][512][4][64][64] 8B 134,217,728
#define OFF_H    ((size_t)155252736)    // [64][512][512] f32      67,108,864

__device__ __forceinline__ uint32 bf16r(float x){
  uint32 u = __float_as_uint(x);
  u += 0x7FFFu + ((u>>16)&1u);
  return u>>16;
}
__device__ __forceinline__ float sigm(float x){
  return __builtin_amdgcn_rcpf(1.f + __builtin_amdgcn_exp2f(-1.4426950408889634f*x));
}
__device__ __forceinline__ float tanh_(float x){
  return 1.f - 2.f*__builtin_amdgcn_rcpf(1.f + __builtin_amdgcn_exp2f(2.8853900817779268f*x));
}

// ---------------- conversions: emb + Wih -> bf16 padded to K=320 ----------------
__global__ void k_convert(const float* __restrict__ emb,
                          const float* __restrict__ wih_f,
                          const float* __restrict__ wih_b,
                          char* __restrict__ ws){
  int tid = blockIdx.x*256 + threadIdx.x;
  const int NE = V_N*40;
  unsigned short* eo = (unsigned short*)(ws + OFF_EMB);
  unsigned short* wo = (unsigned short*)(ws + OFF_WIH);
  const float* src; unsigned short* dst; int g;
  if (tid < NE){
    int row = tid/40; g = tid%40;
    src = emb + (size_t)row*E_N;
    dst = eo + (size_t)row*EPAD + g*8;
  } else if (tid < NE + 2*G_N*40){
    int t2 = tid - NE;
    int dir = t2/(G_N*40); int r2 = t2%(G_N*40);
    int row = r2/40; g = r2%40;
    src = (dir? wih_b : wih_f) + (size_t)row*E_N;
    dst = wo + ((size_t)dir*G_N + row)*EPAD + g*8;
  } else return;
  unsigned short v[8];
  #pragma unroll
  for (int j=0;j<8;j++){
    int c = g*8+j;
    float x = (c < E_N)? src[c] : 0.f;
    v[j] = (unsigned short)bf16r(x);
  }
  uint4 pk;
  pk.x = (uint32)v[0] | ((uint32)v[1]<<16);
  pk.y = (uint32)v[2] | ((uint32)v[3]<<16);
  pk.z = (uint32)v[4] | ((uint32)v[5]<<16);
  pk.w = (uint32)v[6] | ((uint32)v[7]<<16);
  *(uint4*)dst = pk;
}

// ---------------- Whh -> fp8 e4m3 (x64) in 16x16x128 B-operand layout ----------------
__global__ void k_whh(const float* __restrict__ whh_f, const float* __restrict__ whh_b,
                      char* __restrict__ ws){
  int tid = blockIdx.x*256 + threadIdx.x;   // 65536 total
  int part = tid&3;
  int lane = (tid>>2)&63;
  int kk = (tid>>8)&1, tt = (tid>>9)&7, w = (tid>>12)&7, dir = (tid>>15)&1;
  const float* W = dir? whh_b : whh_f;
  int n = lane&15, lq = lane>>4;
  int col = (tt>>1)*256 + w*32 + (tt&1)*16 + n;   // gate*256 + unit
  int k0  = kk*128 + lq*32 + part*8;
  const float* p = W + (size_t)col*H_N + k0;
  int lo = __builtin_amdgcn_cvt_pk_fp8_f32(p[0]*64.f, p[1]*64.f, 0, false);
  lo = __builtin_amdgcn_cvt_pk_fp8_f32(p[2]*64.f, p[3]*64.f, lo, true);
  int hi = __builtin_amdgcn_cvt_pk_fp8_f32(p[4]*64.f, p[5]*64.f, 0, false);
  hi = __builtin_amdgcn_cvt_pk_fp8_f32(p[6]*64.f, p[7]*64.f, hi, true);
  u64 v = (uint32)lo | ((u64)(uint32)hi<<32);
  ((u64*)(ws+OFF_WHH))[tid] = v;
}

// ---------------- input projection: pre = emb[ids] @ Wih^T + bias (bf16 MFMA) -------------
__global__ __launch_bounds__(256,2)
void k_gemm1(const int* __restrict__ ids, char* __restrict__ ws,
             const float* __restrict__ bih_f, const float* __restrict__ bhh_f,
             const float* __restrict__ bih_b, const float* __restrict__ bhh_b){
  int bx = blockIdx.x;                      // [dir(2)][tp(256)][nc(8)]
  int nc = bx & 7, tp = (bx>>3)&255, dir = bx>>11;
  const unsigned short* embb = (const unsigned short*)(ws+OFF_EMB);
  const unsigned short* wihb = (const unsigned short*)(ws+OFF_WIH) + (size_t)dir*G_N*EPAD;
  __shared__ unsigned short Asl[128*32];
  __shared__ unsigned short Bsl[128*32];
  __shared__ int ids_s[128];
  int tid = threadIdx.x, lane = tid&63, w = tid>>6;
  if (tid < 128){
    int t = tp*2 + (tid>>6), b = tid&63;
    ids_s[tid] = ids[b*S_N + t];
  }
  __syncthreads();
  v4f acc[2][8];
  #pragma unroll
  for (int i=0;i<2;i++)
    #pragma unroll
    for (int j=0;j<8;j++) acc[i][j] = (v4f){0.f,0.f,0.f,0.f};
  int r = tid>>1, hf = tid&1;
  int n0 = lane&15, q = lane>>4;
  const float* bi = dir? bih_b : bih_f;
  const float* bh = dir? bhh_b : bhh_f;
  float bv[8];
  #pragma unroll
  for (int nt=0; nt<8; nt++){
    int c = nc*128 + nt*16 + n0;
    bv[nt] = bi[c] + bh[c];
  }
  for (int ks=0; ks<10; ks++){
    const float4* pa = (const float4*)(embb + (size_t)ids_s[r]*EPAD + ks*32 + hf*16);
    float4 a0 = pa[0], a1 = pa[1];
    const float4* pb = (const float4*)(wihb + (size_t)(nc*128 + r)*EPAD + ks*32 + hf*16);
    float4 b0 = pb[0], b1 = pb[1];
    __syncthreads();
    float4* da = (float4*)(Asl + r*32 + hf*16); da[0]=a0; da[1]=a1;
    float4* db = (float4*)(Bsl + r*32 + hf*16); db[0]=b0; db[1]=b1;
    __syncthreads();
    bf16x8 bfr[8], afr[2];
    #pragma unroll
    for (int nt=0; nt<8; nt++) bfr[nt] = *(const bf16x8*)(Bsl + (nt*16+n0)*32 + q*8);
    afr[0] = *(const bf16x8*)(Asl + (w*16+n0)*32 + q*8);
    afr[1] = *(const bf16x8*)(Asl + ((w+4)*16+n0)*32 + q*8);
    #pragma unroll
    for (int mi=0; mi<2; mi++)
      #pragma unroll
      for (int nt=0; nt<8; nt++)
        acc[mi][nt] = __builtin_amdgcn_mfma_f32_16x16x32_bf16(afr[mi], bfr[nt], acc[mi][nt], 0,0,0);
  }
  uint2* pre = (uint2*)(ws + OFF_PRE);
  #pragma unroll
  for (int mi=0; mi<2; mi++){
    int t = tp*2 + mi;
    #pragma unroll
    for (int nt=0; nt<8; nt++){
      int ct = nc*8 + nt;
      size_t tile = (((size_t)(dir*S_N + t)*4 + w)*64 + ct);
      v4f a = acc[mi][nt];
      uint2 o;
      o.x = bf16r(a[0]+bv[nt]) | (bf16r(a[1]+bv[nt])<<16);
      o.y = bf16r(a[2]+bv[nt]) | (bf16r(a[3]+bv[nt])<<16);
      pre[tile*64 + lane] = o;
    }
  }
}

// ---------------- recurrence: R5 structure + setprio MFMA bursts + hoisted polls --------
// grid 64: [dir(1)][bg(2)][q(3)], block 512 (8 waves), wave w owns units [32w,32w+32)
// waves 0..3 produce h_low (units 0..127) -> ctr[0]; waves 4..7 -> h_high -> ctr[1].
#define MFMA_SC(A,B,C) __builtin_amdgcn_mfma_scale_f32_16x16x128_f8f6f4( \
    (A), (B), (C), 0, 0, 0, 0x7F7F7F7F, 0, 0x75757575)

template<int R0>
__device__ __forceinline__ void lstm_loop(
    const char* pp, int sstride, const int* voff, int ab,
    const v8i (*Wf)[2], float* scw, int n0, bool act,
    char* hb0, char* hb1, int hb_off, float* hp, int hstride,
    int lane, int hw, volatile int* vc, int* ctrs)
{
  uint32 pr[8];
  #pragma unroll
  for (int tt=0;tt<8;tt++) pr[tt] = 0u;
  if (act){
    #pragma unroll
    for (int tt=0;tt<8;tt++) pr[tt] = *(const uint32*)(pp + voff[tt]);
  }
  pp += sstride;
  float c0 = 0.f;
  v4f acc[8];
  #pragma unroll
  for (int tt=0;tt<8;tt++) acc[tt] = (v4f){0.f,0.f,0.f,0.f};
  char* hbr = hb0; char* hbw = hb1;
  int rb = (((lane>>4)&1)*16 + n0)*2 + (lane>>5);   // gate-scratch read base
  #pragma unroll 1
  for (int step=0; step<S_N; step++){
    int need = 4*step;
    // ---- wait both producer groups up front (steady-state: near-free) ----
    while (vc[0] < need) __builtin_amdgcn_s_sleep(1);
    while (vc[1] < need) __builtin_amdgcn_s_sleep(1);
    v8i afr0, afr1;
    { v4i lo = *(const v4i*)(hbr + ab);       v4i hi = *(const v4i*)(hbr + ab + 16);
      afr0 = __builtin_shufflevector(lo,hi,0,1,2,3,4,5,6,7); }
    { v4i lo = *(const v4i*)(hbr + ab + 128); v4i hi = *(const v4i*)(hbr + ab + 144);
      afr1 = __builtin_shufflevector(lo,hi,0,1,2,3,4,5,6,7); }
    if (act){
      #pragma unroll
      for (int tt=0;tt<8;tt++){
        acc[tt][R0]   = __uint_as_float(pr[tt]<<16);
        acc[tt][R0+1] = __uint_as_float(pr[tt] & 0xFFFF0000u);
      }
      #pragma unroll
      for (int tt=0;tt<8;tt++) pr[tt] = *(const uint32*)(pp + voff[tt]);
    }
    pp += sstride;
    // ---- unbroken 16-MFMA burst at raised priority (de-phase waves) ----
    __builtin_amdgcn_s_setprio(1);
    #pragma unroll
    for (int tt=0;tt<8;tt++) acc[tt] = MFMA_SC(afr0, Wf[tt][0], acc[tt]);
    #pragma unroll
    for (int tt=0;tt<8;tt++) acc[tt] = MFMA_SC(afr1, Wf[tt][1], acc[tt]);
    __builtin_amdgcn_s_setprio(0);
    // ---- gates -> per-wave LDS scratch (layout [g][uh][n0][mb]) ----
    if (act){
      #pragma unroll
      for (int tt=0;tt<8;tt++){
        int g = tt>>1, uh = tt&1;
        v2f gp = (v2f){ acc[tt][R0], acc[tt][R0+1] };
        *(v2f*)(scw + ((g*2+uh)*16 + n0)*2) = gp;
      }
    }
    float g0 = scw[rb], g1 = scw[rb+64], g2 = scw[rb+128], g3 = scw[rb+192];
    float si = sigm(g0), sf = sigm(g1);
    float tg = tanh_(g2), so = sigm(g3);
    c0 = sf*c0 + si*tg;
    float h = so * tanh_(c0);
    int pk8 = __builtin_amdgcn_cvt_pk_fp8_f32(h*16.f, 0.f, 0, false);
    hbw[hb_off] = (char)(pk8 & 0xFF);
    *hp = h; hp += hstride;
    if (lane == 0) atomicAdd(&ctrs[hw], 1);
    char* t = hbr; hbr = hbw; hbw = t;
  }
}

__global__ __launch_bounds__(512,2)
void k_lstm(char* __restrict__ ws){
  int bx = blockIdx.x;
  int q = bx&7, bg = (bx>>3)&3, dir = bx>>5;
  int tid = threadIdx.x, lane = tid&63, w = tid>>6;
  int n0 = lane&15, lq = lane>>4;
  __shared__ char hbuf[2][16*272];       // h (fp8 x16), stride 272
  __shared__ float gsc[8][256];          // per-wave [g][uh][n0][mb]
  __shared__ int ctrs[2];
  for (int i=tid; i<2176; i+=512) ((int*)hbuf)[i] = 0;
  if (tid < 2) ctrs[tid] = 0;
  // weights: per (dir,w) 32 KB block, per (tt,kk) 64 lanes x 32 B
  const v8i* wp = (const v8i*)(ws + OFF_WHH + (size_t)(dir*8+w)*32768);
  v8i Wf[8][2];
  #pragma unroll
  for (int tt=0; tt<8; tt++)
    #pragma unroll
    for (int kk=0; kk<2; kk++)
      Wf[tt][kk] = wp[(tt*2+kk)*64 + lane];
  // ---- precomputed step-invariant state ----
  int st0 = dir? (S_N-1) : 0;
  const char* pp = ws + OFF_PRE + (size_t)dir*67108864 + (size_t)(st0*4 + bg)*32768;
  const int sstride = dir? -131072 : 131072;
  int voff[8];
  #pragma unroll
  for (int tt=0; tt<8; tt++){
    int g = tt>>1, uh = tt&1;
    int ct = g*16 + w*2 + uh;
    voff[tt] = (ct*64 + lane)*8 + (q&1)*4;
  }
  int ab = n0*272 + lq*32;               // afr base (bytes) within hbuf half
  float* scw = gsc[w];
  bool act = (lq == (q>>1));
  // per-lane epilogue assignment: mb=lane>>5, uh0=(lane>>4)&1, n0
  int mb = lane>>5, uh0 = (lane>>4)&1;
  int u0 = w*32 + uh0*16 + n0;
  int row = 2*q + mb;                    // batch slot within bg's 16
  int hb_off = row*272 + u0;
  float* hout = (float*)(ws+OFF_H);
  int b = bg*16 + row;
  float* hp = hout + ((size_t)b*S_N + st0)*512 + dir*256 + u0;
  const int hstride = dir? -512 : 512;
  int hw = (w >= 4);
  volatile int* vc = (volatile int*)ctrs;
  __syncthreads();
  if (q & 1)
    lstm_loop<2>(pp, sstride, voff, ab, Wf, scw, n0, act, hbuf[0], hbuf[1],
                 hb_off, hp, hstride, lane, hw, vc, ctrs);
  else
    lstm_loop<0>(pp, sstride, voff, ab, Wf, scw, n0, act, hbuf[0], hbuf[1],
                 hb_off, hp, hstride, lane, hw, vc, ctrs);
}

// ---------------- classifier: one wave per token, f32 ----------------
__global__ __launch_bounds__(256)
void k_clf(const char* __restrict__ ws, const float* __restrict__ clfW,
           const float* __restrict__ clfb, float* __restrict__ out){
  int wid = (blockIdx.x*256 + threadIdx.x)>>6;
  int lane = threadIdx.x & 63;
  const float4* h = (const float4*)((const float*)(ws+OFF_H) + (size_t)wid*512);
  float4 h0 = h[lane*2], h1 = h[lane*2+1];
  float a[9];
  #pragma unroll
  for (int t=0;t<9;t++){
    const float4* wp = (const float4*)(clfW + t*512);
    float4 w0 = wp[lane*2], w1 = wp[lane*2+1];
    a[t] = h0.x*w0.x + h0.y*w0.y + h0.z*w0.z + h0.w*w0.w
         + h1.x*w1.x + h1.y*w1.y + h1.z*w1.z + h1.w*w1.w;
  }
  #pragma unroll
  for (int t=0;t<9;t++){
    #pragma unroll
    for (int m=32;m>=1;m>>=1) a[t] += __shfl_xor(a[t], m, 64);
  }
  float val = a[0];
  #pragma unroll
  for (int t=1;t<9;t++) val = (lane==t)? a[t] : val;
  if (lane<9) out[1 + (size_t)wid*9 + lane] = val + clfb[lane];
}

// ---------------- CRF ----------------
__global__ void k_zero(float* out){ if (threadIdx.x==0 && blockIdx.x==0) out[0]=0.f; }

__global__ __launch_bounds__(64)
void k_crf(const int* __restrict__ labels, const float* __restrict__ start_t,
           const float* __restrict__ end_t, const float* __restrict__ trans,
           float* __restrict__ out){
  int b = blockIdx.x, lane = threadIdx.x;
  const float* em = out + 1 + (size_t)b*S_N*T_N;
  const int* tg = labels + (size_t)b*S_N;
  float scv = 0.f;
  for (int t=lane; t<S_N; t+=64){
    int ct = tg[t];
    float e = em[t*T_N + ct];
    if (t==0) scv += start_t[ct] + e;
    else scv += trans[tg[t-1]*T_N + ct] + e;
  }
  if (lane==0) scv += end_t[tg[S_N-1]];
  #pragma unroll
  for (int m=32;m>=1;m>>=1) scv += __shfl_xor(scv, m, 64);
  int j = (lane<9)? lane : 0;
  float wt[9];
  #pragma unroll
  for (int i=0;i<9;i++) wt[i] = trans[i*T_N + j];
  float alpha = start_t[j] + em[j];
  #pragma unroll 1
  for (int t=1;t<S_N;t++){
    float v[9]; float mx = -3.4e38f;
    #pragma unroll
    for (int i=0;i<9;i++){
      float av = __shfl(alpha, i, 64);
      v[i] = av + wt[i];
      mx = fmaxf(mx, v[i]);
    }
    float ss = 0.f;
    #pragma unroll
    for (int i=0;i<9;i++) ss += __builtin_amdgcn_exp2f(1.4426950408889634f*(v[i]-mx));
    alpha = mx + 0.6931471805599453f*__builtin_amdgcn_logf(ss) + em[t*T_N + j];
  }
  float av = (lane<9)? alpha + end_t[j] : -3.4e38f;
  float mx = av;
  #pragma unroll
  for (int m=32;m>=1;m>>=1) mx = fmaxf(mx, __shfl_xor(mx, m, 64));
  float es = (lane<9)? __builtin_amdgcn_exp2f(1.4426950408889634f*(av-mx)) : 0.f;
  #pragma unroll
  for (int m=32;m>=1;m>>=1) es += __shfl_xor(es, m, 64);
  float logZ = mx + 0.6931471805599453f*__builtin_amdgcn_logf(es);
  if (lane==0) atomicAdd(out, logZ - scv);
}

extern "C" void kernel_launch(void* const* d_in, const int* in_sizes, int n_in,
                              void* d_out, int out_size, void* d_ws, size_t ws_size,
                              hipStream_t stream){
  const int* ids      = (const int*)d_in[0];
  const int* labels   = (const int*)d_in[1];
  const float* emb    = (const float*)d_in[3];
  const float* wih_f  = (const float*)d_in[4];
  const float* whh_f  = (const float*)d_in[5];
  const float* bih_f  = (const float*)d_in[6];
  const float* bhh_f  = (const float*)d_in[7];
  const float* wih_b  = (const float*)d_in[8];
  const float* whh_b  = (const float*)d_in[9];
  const float* bih_b  = (const float*)d_in[10];
  const float* bhh_b  = (const float*)d_in[11];
  const float* clfW   = (const float*)d_in[12];
  const float* clfb   = (const float*)d_in[13];
  const float* start_t= (const float*)d_in[14];
  const float* end_t  = (const float*)d_in[15];
  const float* trans  = (const float*)d_in[16];
  float* out = (float*)d_out;
  char* ws = (char*)d_ws;

  hipLaunchKernelGGL(k_zero, dim3(1), dim3(64), 0, stream, out);
  hipLaunchKernelGGL(k_convert, dim3((V_N*40 + 2*G_N*40 + 255)/256), dim3(256), 0, stream,
                     emb, wih_f, wih_b, ws);
  hipLaunchKernelGGL(k_whh, dim3(256), dim3(256), 0, stream, whh_f, whh_b, ws);
  hipLaunchKernelGGL(k_gemm1, dim3(4096), dim3(256), 0, stream, ids, ws,
                     bih_f, bhh_f, bih_b, bhh_b);
  hipLaunchKernelGGL(k_lstm, dim3(64), dim3(512), 0, stream, ws);
  hipLaunchKernelGGL(k_clf, dim3(8192), dim3(256), 0, stream, ws, clfW, clfb, out);
  hipLaunchKernelGGL(k_crf, dim3(64), dim3(64), 0, stream, labels, start_t, end_t, trans, out);
}